// Round 13
// baseline (4316.187 us; speedup 1.0000x reference)
//
#include <hip/hip_runtime.h>

#define NPTS 8192
#define DIM  128
// K stored as fp8 e4m3 scaled by S=128:  k8 = 128*exp(-C/0.1)
// recurrences on raw sums r = K8 @ w:    w = (128/8192)/(r + 128e-6)
#define WPREP(x) (0.015625f / ((x) + 1.28e-4f))

typedef short s16x8 __attribute__((ext_vector_type(8)));
typedef float f32x4 __attribute__((ext_vector_type(4)));
typedef float f32x2 __attribute__((ext_vector_type(2)));

__device__ __forceinline__ ushort f2bf(float f) {
  unsigned u = __float_as_uint(f);
  u += 0x7fffu + ((u >> 16) & 1u);   // RNE
  return (ushort)(u >> 16);
}
__device__ __forceinline__ float bf2f(ushort b) {
  return __uint_as_float(((unsigned)b) << 16);
}

// ---- fp8 e4m3 encode/decode (HW cvt preferred; self-consistent either way)
__device__ __forceinline__ unsigned char fp8_enc_sw(float f) {
  if (f < 0.015625f) {                       // subnormal: step 2^-9
    int mi = (int)rintf(f * 512.0f);
    return (unsigned char)(mi >= 8 ? 0x08 : mi);
  }
  unsigned u = __float_as_uint(f);
  unsigned r = u + 0xfffffu + ((u >> 20) & 1u);  // RNE to 3 mantissa bits
  int e = (int)((r >> 23) & 0xff) - 127;
  unsigned mant = (r >> 20) & 7u;
  if (e > 8 || (e == 8 && mant > 6)) return 0x7e;  // saturate 448
  return (unsigned char)(((e + 7) << 3) | mant);
}
__device__ __forceinline__ float fp8_dec_sw(unsigned b) {
  unsigned E = (b >> 3) & 15u, M = b & 7u;
  float n = __uint_as_float(((E + 120u) << 23) | (M << 20));
  float s = (float)M * 0.001953125f;
  return E ? n : s;
}
__device__ __forceinline__ unsigned char enc1(float f) {
#if __has_builtin(__builtin_amdgcn_cvt_pk_fp8_f32)
  return (unsigned char)(__builtin_amdgcn_cvt_pk_fp8_f32(f, f, 0, false) & 0xff);
#else
  return fp8_enc_sw(f);
#endif
}
template <bool HI>
__device__ __forceinline__ f32x2 dec2(unsigned w) {
#if __has_builtin(__builtin_amdgcn_cvt_pk_f32_fp8)
  return __builtin_amdgcn_cvt_pk_f32_fp8((int)w, HI);
#else
  f32x2 r;
  r.x = fp8_dec_sw(HI ? ((w >> 16) & 0xffu) : (w & 0xffu));
  r.y = fp8_dec_sw(HI ? (w >> 24) : ((w >> 8) & 0xffu));
  return r;
#endif
}

// LDS swizzle for the w[] vector (2-way max conflicts for lane*16 strides)
__device__ __forceinline__ int swz(int j) { return j + 2 * (j >> 5); }
#define WSZ (NPTS + 2 * (NPTS / 32) + 8)   // 8712 floats

// ---------------------------------------------------------------- zero two 8192-float buffers
__global__ __launch_bounds__(256) void init_zero2(float* __restrict__ a,
                                                  float* __restrict__ b) {
  int j = blockIdx.x * 256 + threadIdx.x;
  a[j] = 0.0f; b[j] = 0.0f;
}

// ---------------------------------------------------------------- x2 = sum(bf16(x)^2)
__global__ __launch_bounds__(256) void sq_rows(const float* __restrict__ X,
                                               const float* __restrict__ Y,
                                               float* __restrict__ x2,
                                               float* __restrict__ y2) {
  int wave = threadIdx.x >> 6, lane = threadIdx.x & 63;
  int row = blockIdx.x * 4 + wave;               // 0..16383
  const float* src = (row < NPTS) ? X + (size_t)row * DIM
                                  : Y + (size_t)(row - NPTS) * DIM;
  float2 v = *reinterpret_cast<const float2*>(src + lane * 2);
  float ax = bf2f(f2bf(v.x)), ay = bf2f(f2bf(v.y));
  float s = ax * ax + ay * ay;
  for (int off = 32; off; off >>= 1) s += __shfl_down(s, off, 64);
  if (lane == 0) {
    if (row < NPTS) x2[row] = s; else y2[row - NPTS] = s;
  }
}

// ---------------------------------------------------------------- K8 = fp8(128*exp(-10*max(a2+b2-2*A.B^T,0)))
__global__ __launch_bounds__(256) void build_k(const float* __restrict__ A,
                                               const float* __restrict__ B,
                                               const float* __restrict__ a2,
                                               const float* __restrict__ b2,
                                               unsigned char* __restrict__ K8) {
  __shared__ ushort At[128][136];   // +8 pad
  __shared__ ushort Bt[128][136];
  int t = threadIdx.x;
  int tm = blockIdx.x, tn = blockIdx.y;
  {
    int r = t >> 1;
    int c0 = (t & 1) * 64;
    const float* Ar = A + (size_t)(tm * 128 + r) * DIM + c0;
    const float* Br = B + (size_t)(tn * 128 + r) * DIM + c0;
    for (int c = 0; c < 64; c += 4) {
      float4 av = *reinterpret_cast<const float4*>(Ar + c);
      float4 bv = *reinterpret_cast<const float4*>(Br + c);
      unsigned pa0 = (unsigned)f2bf(av.x) | ((unsigned)f2bf(av.y) << 16);
      unsigned pa1 = (unsigned)f2bf(av.z) | ((unsigned)f2bf(av.w) << 16);
      unsigned pb0 = (unsigned)f2bf(bv.x) | ((unsigned)f2bf(bv.y) << 16);
      unsigned pb1 = (unsigned)f2bf(bv.z) | ((unsigned)f2bf(bv.w) << 16);
      *reinterpret_cast<unsigned*>(&At[r][c0 + c + 0]) = pa0;
      *reinterpret_cast<unsigned*>(&At[r][c0 + c + 2]) = pa1;
      *reinterpret_cast<unsigned*>(&Bt[r][c0 + c + 0]) = pb0;
      *reinterpret_cast<unsigned*>(&Bt[r][c0 + c + 2]) = pb1;
    }
  }
  __syncthreads();
  int wave = t >> 6, lane = t & 63;
  int lr = lane & 15;            // A-row / B-col within 16-tile
  int lk = (lane >> 4) * 8;      // k offset
  f32x4 acc[2][8];
  for (int mi = 0; mi < 2; ++mi)
    for (int ni = 0; ni < 8; ++ni)
      acc[mi][ni] = (f32x4){0.f, 0.f, 0.f, 0.f};
  for (int kc = 0; kc < 4; ++kc) {
    s16x8 af[2], bfr[8];
    af[0] = *reinterpret_cast<const s16x8*>(&At[wave * 32 + lr][kc * 32 + lk]);
    af[1] = *reinterpret_cast<const s16x8*>(&At[wave * 32 + 16 + lr][kc * 32 + lk]);
    for (int ni = 0; ni < 8; ++ni)
      bfr[ni] = *reinterpret_cast<const s16x8*>(&Bt[ni * 16 + lr][kc * 32 + lk]);
    for (int mi = 0; mi < 2; ++mi)
      for (int ni = 0; ni < 8; ++ni)
        acc[mi][ni] = __builtin_amdgcn_mfma_f32_16x16x32_bf16(af[mi], bfr[ni],
                                                              acc[mi][ni], 0, 0, 0);
  }
  // D layout: col = lane&15, row = (lane>>4)*4 + reg  [verified m89/m91]
  int drow = (lane >> 4) * 4;
  float a2r[2][4], b2c[8];
  for (int mi = 0; mi < 2; ++mi)
    for (int r = 0; r < 4; ++r) a2r[mi][r] = a2[tm * 128 + wave * 32 + mi * 16 + drow + r];
  for (int ni = 0; ni < 8; ++ni) b2c[ni] = b2[tn * 128 + ni * 16 + lr];
  __syncthreads();  // all LDS frag reads done; reuse At region as byte tile
  unsigned char (*O)[144] = reinterpret_cast<unsigned char (*)[144]>(&At[0][0]);
  for (int mi = 0; mi < 2; ++mi)
    for (int ni = 0; ni < 8; ++ni)
      for (int r = 0; r < 4; ++r) {
        float S = acc[mi][ni][r];
        float C = fmaxf(a2r[mi][r] + b2c[ni] - 2.0f * S, 0.0f);
        // 128*exp(-C/0.1) = 2^(7 - C*10/ln2)
        float kv = exp2f(7.0f - 14.426950408889634f * C);
        O[wave * 32 + mi * 16 + drow + r][ni * 16 + lr] = enc1(kv);
      }
  __syncthreads();
  int row = t >> 1, half = t & 1;
  const uint4* src = reinterpret_cast<const uint4*>(&O[row][half * 64]);
  uint4* dst = reinterpret_cast<uint4*>(K8 + (size_t)(tm * 128 + row) * NPTS + tn * 128 + half * 64);
#pragma unroll
  for (int k = 0; k < 4; ++k) dst[k] = src[k];
}

// ---------------------------------------------------------------- symmetric matvec pass
// One upper-triangle 256x256 tile per block (528 tiles, 512 threads, 64KB fetch).
// Row-dots from load registers; col-dots (off-diag) via word-granular LDS reads:
// 64 col-groups (4 cols) x 8 row-groups (32 rows). atomicAdd over 8192 addrs.
__global__ __launch_bounds__(512) void sympass2(const unsigned char* __restrict__ KA,
                                                const unsigned char* __restrict__ KB,
                                                const float* __restrict__ inA,
                                                const float* __restrict__ inB,
                                                float* __restrict__ accA,
                                                float* __restrict__ accB,
                                                float* __restrict__ znA,
                                                float* __restrict__ znB,
                                                int init) {
  __shared__ unsigned char T[256][268];   // 268B = 67 dwords/row; 67%32=3 -> banks spread
  __shared__ float wj[256], wi[256];
  __shared__ float cp[8][257];            // 257-stride: scalar stores 2-way max
  int half = blockIdx.y;
  const unsigned char* K8 = half ? KB : KA;
  const float* in = half ? inB : inA;
  float* acc = half ? accB : accA;
  float* zn = half ? znB : znA;
  int tid = blockIdx.x;
  int t = threadIdx.x;
  if (tid < 16) zn[tid * 512 + t] = 0.0f;   // zero pass p+1's acc target
  // tile coords: upper triangle of 32, row-major; prefix(i) = i*32 - i*(i-1)/2
  int bi = (int)(32.5f - sqrtf(32.5f * 32.5f - 2.0f * (float)tid));
  if (bi < 0) bi = 0; if (bi > 31) bi = 31;
  while (bi > 0 && tid < bi * 32 - bi * (bi - 1) / 2) --bi;
  while (tid >= (bi + 1) * 32 - (bi + 1) * bi / 2) ++bi;
  int bj = bi + tid - (bi * 32 - bi * (bi - 1) / 2);
  if (t < 256) wj[t] = init ? 1.0f : WPREP(in[bj * 256 + t]);
  else         wi[t - 256] = init ? 1.0f : WPREP(in[bi * 256 + (t - 256)]);
  int r = t >> 1, h = t & 1;   // row r (0..255), half-row h (128 B each)
  const unsigned char* src = K8 + (size_t)(bi * 256 + r) * NPTS + bj * 256 + h * 128;
  uint4 q[8];
#pragma unroll
  for (int k = 0; k < 8; ++k) q[k] = *reinterpret_cast<const uint4*>(src + 16 * k);
  bool offdiag = (bi != bj);
  if (offdiag) {
#pragma unroll
    for (int k = 0; k < 8; ++k)
      *reinterpret_cast<uint4*>(&T[r][h * 128 + 16 * k]) = q[k];
  }
  __syncthreads();
  // ROW phase: y[bi*256+r] += sum_c K[r][c]*wj[c]   (from registers)
  float racc = 0.f;
#pragma unroll
  for (int k = 0; k < 8; ++k) {
    const unsigned* p = &q[k].x;
#pragma unroll
    for (int e = 0; e < 4; ++e) {
      f32x2 lo = dec2<false>(p[e]), hi2 = dec2<true>(p[e]);
      int c = h * 128 + k * 16 + e * 4;
      racc = fmaf(lo.x, wj[c], racc);
      racc = fmaf(lo.y, wj[c + 1], racc);
      racc = fmaf(hi2.x, wj[c + 2], racc);
      racc = fmaf(hi2.y, wj[c + 3], racc);
    }
  }
  racc += __shfl_xor(racc, 1, 64);   // combine half-rows (lanes 2r, 2r+1)
  if (h == 0) atomicAdd(&acc[bi * 256 + r], racc);
  // COL phase (off-diag): y[bj*256+c] += sum_r T[r][c]*wi[r]
  // thread = (col-group cg: 4 cols) x (row-group rg: 32 rows); word reads.
  if (offdiag) {
    int cg = t >> 3, rg = t & 7;   // cg 0..63 (256 cols), rg 0..7 (32 rows each)
    float c0 = 0.f, c1 = 0.f, c2 = 0.f, c3 = 0.f;
#pragma unroll
    for (int i = 0; i < 32; ++i) {
      int row = rg * 32 + ((i + rg * 4) & 31);   // de-phase row groups across banks
      unsigned v = *reinterpret_cast<const unsigned*>(&T[row][cg * 4]);
      float wr = wi[row];
      f32x2 lo = dec2<false>(v), hi2 = dec2<true>(v);
      c0 = fmaf(lo.x, wr, c0);
      c1 = fmaf(lo.y, wr, c1);
      c2 = fmaf(hi2.x, wr, c2);
      c3 = fmaf(hi2.y, wr, c3);
    }
    cp[rg][cg * 4 + 0] = c0;
    cp[rg][cg * 4 + 1] = c1;
    cp[rg][cg * 4 + 2] = c2;
    cp[rg][cg * 4 + 3] = c3;
    __syncthreads();
    if (t < 256) {
      float s = (((cp[0][t] + cp[1][t]) + (cp[2][t] + cp[3][t])) +
                 ((cp[4][t] + cp[5][t]) + (cp[6][t] + cp[7][t])));
      atomicAdd(&acc[bj * 256 + t], s);
    }
  }
}

// ---------------------------------------------------------------- shared row-matvec core (XY)
// 512-thread blocks: 8 waves x 2 rows = 16 rows/block, one shared w[] copy.
__device__ __forceinline__ void prep_w(float* w, const float* __restrict__ in, int init, int t) {
  if (init) {
#pragma unroll
    for (int k = 0; k < 16; ++k) w[swz(t + 512 * k)] = 1.0f;
  } else {
    float tmp[16];
#pragma unroll
    for (int k = 0; k < 16; ++k) tmp[k] = in[t + 512 * k];
#pragma unroll
    for (int k = 0; k < 16; ++k) w[swz(t + 512 * k)] = WPREP(tmp[k]);
  }
}

// depth-2 pipelined row-matvec: 4 loads in flight per wave.
__device__ __forceinline__ void row_block(const unsigned char* __restrict__ K8,
                                          float* __restrict__ out,
                                          int row0, int t, const float* w) {
  int lane = t & 63;
  const unsigned char* K0 = K8 + (size_t)row0 * NPTS + lane * 16;
  const unsigned char* K1 = K0 + NPTS;
  float a0 = 0.f, b0 = 0.f, a1 = 0.f, b1 = 0.f;
  uint4 c0 = *reinterpret_cast<const uint4*>(K0);
  uint4 c1 = *reinterpret_cast<const uint4*>(K1);
#pragma unroll
  for (int rnd = 0; rnd < 8; ++rnd) {
    uint4 n0 = c0, n1 = c1;
    if (rnd < 7) {
      n0 = *reinterpret_cast<const uint4*>(K0 + (rnd + 1) * 1024);
      n1 = *reinterpret_cast<const uint4*>(K1 + (rnd + 1) * 1024);
    }
    int pb = swz(rnd * 1024 + lane * 16);
    const unsigned* p0 = &c0.x;
    const unsigned* p1 = &c1.x;
#pragma unroll
    for (int e = 0; e < 4; ++e) {
      f32x2 w0 = *reinterpret_cast<const f32x2*>(&w[pb + 4 * e]);
      f32x2 w1 = *reinterpret_cast<const f32x2*>(&w[pb + 4 * e + 2]);
      f32x2 k0l = dec2<false>(p0[e]), k0h = dec2<true>(p0[e]);
      f32x2 k1l = dec2<false>(p1[e]), k1h = dec2<true>(p1[e]);
      a0 = fmaf(k0l.x, w0.x, a0); b0 = fmaf(k0l.y, w0.y, b0);
      a0 = fmaf(k0h.x, w1.x, a0); b0 = fmaf(k0h.y, w1.y, b0);
      a1 = fmaf(k1l.x, w0.x, a1); b1 = fmaf(k1l.y, w0.y, b1);
      a1 = fmaf(k1h.x, w1.x, a1); b1 = fmaf(k1h.y, w1.y, b1);
    }
    c0 = n0; c1 = n1;
  }
  float s0 = a0 + b0, s1 = a1 + b1;
  for (int off = 32; off; off >>= 1) {
    s0 += __shfl_down(s0, off, 64);
    s1 += __shfl_down(s1, off, 64);
  }
  if (lane == 0) { out[row0] = s0; out[row0 + 1] = s1; }
}

// xy row step: also zeroes the buffer the following colpass will atomically fill
__global__ __launch_bounds__(512) void rowpass_xy(const unsigned char* __restrict__ K8,
                                                  const float* __restrict__ in,
                                                  float* __restrict__ out,
                                                  float* __restrict__ vzero,
                                                  int init) {
  __shared__ float w[WSZ];
  int t = threadIdx.x;
  if (t < 16) vzero[blockIdx.x * 16 + t] = 0.0f;
  prep_w(w, in, init, t);
  __syncthreads();
  int row0 = blockIdx.x * 16 + (t >> 6) * 2;
  row_block(K8, out, row0, t, w);
}

// ---------------------------------------------------------------- vout[j] += sum_i K8[i][j]*u_i (atomic)
__global__ __launch_bounds__(256) void colpass(const unsigned char* __restrict__ K8,
                                               const float* __restrict__ uraw,
                                               float* __restrict__ vout) {
  __shared__ float us[64];
  int t = threadIdx.x;
  int jb = blockIdx.x;       // 0..7 (1024 cols each)
  int ic = blockIdx.y;       // 0..127 (64 rows each)
  int i0 = ic * 64;
  if (t < 64) us[t] = WPREP(uraw[i0 + t]);
  __syncthreads();
  int j0 = jb * 1024 + t * 4;
  float acc0 = 0.f, acc1 = 0.f, acc2 = 0.f, acc3 = 0.f;
  for (int i = 0; i < 64; i += 8) {
    unsigned wv[8];
#pragma unroll
    for (int k = 0; k < 8; ++k)
      wv[k] = *reinterpret_cast<const unsigned*>(K8 + (size_t)(i0 + i + k) * NPTS + j0);
#pragma unroll
    for (int k = 0; k < 8; ++k) {
      float uu = us[i + k];
      f32x2 lo = dec2<false>(wv[k]), hi = dec2<true>(wv[k]);
      acc0 = fmaf(lo.x, uu, acc0);
      acc1 = fmaf(lo.y, uu, acc1);
      acc2 = fmaf(hi.x, uu, acc2);
      acc3 = fmaf(hi.y, uu, acc3);
    }
  }
  atomicAdd(&vout[j0 + 0], acc0);
  atomicAdd(&vout[j0 + 1], acc1);
  atomicAdd(&vout[j0 + 2], acc2);
  atomicAdd(&vout[j0 + 3], acc3);
}

// ---------------------------------------------------------------- partial[wg] = sum_rows u_i * sum_j K*C*v_j
// C = -0.1*ln(k8/128) = 0.0693147*(7 - log2 k8);  K = k8/128 folded into u at the end
__global__ __launch_bounds__(256) void costpass(const unsigned char* __restrict__ K8,
                                                const float* __restrict__ uraw,
                                                const float* __restrict__ vraw,
                                                float* __restrict__ partial) {
  __shared__ float w[WSZ];
  __shared__ float wsum[4];
  int t = threadIdx.x;
  {
    float tmp[32];
#pragma unroll
    for (int k = 0; k < 32; ++k) tmp[k] = vraw[t + 256 * k];
#pragma unroll
    for (int k = 0; k < 32; ++k) w[swz(t + 256 * k)] = WPREP(tmp[k]);
  }
  __syncthreads();
  int wave = t >> 6, lane = t & 63;
  int row = blockIdx.x * 4 + wave;
  const unsigned char* Kr = K8 + (size_t)row * NPTS + lane * 16;
  float acc = 0.f;
  uint4 c = *reinterpret_cast<const uint4*>(Kr);
#pragma unroll
  for (int rnd = 0; rnd < 8; ++rnd) {
    uint4 n = c;
    if (rnd < 7) n = *reinterpret_cast<const uint4*>(Kr + (rnd + 1) * 1024);
    const unsigned* p = &c.x;
    int pb = swz(rnd * 1024 + lane * 16);
#pragma unroll
    for (int e = 0; e < 4; ++e) {
      f32x2 w0 = *reinterpret_cast<const f32x2*>(&w[pb + 4 * e]);
      f32x2 w1 = *reinterpret_cast<const f32x2*>(&w[pb + 4 * e + 2]);
      f32x2 kl = dec2<false>(p[e]), kh = dec2<true>(p[e]);
      float c0 = (kl.x > 0.f) ? 0.069314718f * (7.0f - __log2f(kl.x)) : 0.f;
      float c1 = (kl.y > 0.f) ? 0.069314718f * (7.0f - __log2f(kl.y)) : 0.f;
      float c2 = (kh.x > 0.f) ? 0.069314718f * (7.0f - __log2f(kh.x)) : 0.f;
      float c3 = (kh.y > 0.f) ? 0.069314718f * (7.0f - __log2f(kh.y)) : 0.f;
      acc = fmaf(kl.x * c0, w0.x, acc);
      acc = fmaf(kl.y * c1, w0.y, acc);
      acc = fmaf(kh.x * c2, w1.x, acc);
      acc = fmaf(kh.y * c3, w1.y, acc);
    }
    c = n;
  }
  for (int off = 32; off; off >>= 1) acc += __shfl_down(acc, off, 64);
  if (lane == 0) {
    float u = WPREP(uraw[row]);
    wsum[wave] = acc * u * 0.0078125f;   // fold K = k8/128
  }
  __syncthreads();
  if (t == 0) partial[blockIdx.x] = (wsum[0] + wsum[1]) + (wsum[2] + wsum[3]);
}

// ---------------------------------------------------------------- div = max(cxy - 0.5*(cxx+cyy), 0)
__global__ __launch_bounds__(256) void final_combine(const float* __restrict__ pxy,
                                                     const float* __restrict__ pxx,
                                                     const float* __restrict__ pyy,
                                                     float* __restrict__ out) {
  __shared__ float buf[3][256];
  int t = threadIdx.x;
  float s0 = 0.f, s1 = 0.f, s2 = 0.f;
  for (int i = t; i < 2048; i += 256) { s0 += pxy[i]; s1 += pxx[i]; s2 += pyy[i]; }
  buf[0][t] = s0; buf[1][t] = s1; buf[2][t] = s2;
  __syncthreads();
  for (int off = 128; off; off >>= 1) {
    if (t < off) {
      buf[0][t] += buf[0][t + off];
      buf[1][t] += buf[1][t + off];
      buf[2][t] += buf[2][t + off];
    }
    __syncthreads();
  }
  if (t == 0) {
    float div = buf[0][0] - 0.5f * (buf[1][0] + buf[2][0]);
    if (!isfinite(div)) div = 0.0f;
    out[0] = fmaxf(div, 0.0f);
  }
}

// ----------------------------------------------------------------
extern "C" void kernel_launch(void* const* d_in, const int* in_sizes, int n_in,
                              void* d_out, int out_size, void* d_ws, size_t ws_size,
                              hipStream_t stream) {
  const float* X = (const float*)d_in[0];
  const float* Y = (const float*)d_in[1];
  float* out = (float*)d_out;
  char* ws = (char*)d_ws;

  size_t off = 0;
  unsigned char* KA = (unsigned char*)(ws + off); off += (size_t)NPTS * NPTS;  // 67 MB
  unsigned char* KB = (unsigned char*)(ws + off); off += (size_t)NPTS * NPTS;  // 67 MB
  float* zA[3]; float* zB[3];
  for (int i = 0; i < 3; ++i) { zA[i] = (float*)(ws + off); off += (size_t)NPTS * 4; }
  for (int i = 0; i < 3; ++i) { zB[i] = (float*)(ws + off); off += (size_t)NPTS * 4; }
  float* rxy  = (float*)(ws + off); off += (size_t)NPTS * 4;
  float* vab0 = (float*)(ws + off); off += (size_t)NPTS * 4;
  float* vab1 = (float*)(ws + off); off += (size_t)NPTS * 4;
  float* x2   = (float*)(ws + off); off += (size_t)NPTS * 4;
  float* y2   = (float*)(ws + off); off += (size_t)NPTS * 4;
  float* pxy  = (float*)(ws + off); off += 2048 * 4;
  float* pxx  = (float*)(ws + off); off += 2048 * 4;
  float* pyy  = (float*)(ws + off); off += 2048 * 4;
  if (ws_size < off) {
    (void)hipMemsetAsync(d_out, 0, sizeof(float), stream);
    return;
  }
  float* vab[2] = {vab0, vab1};

  init_zero2<<<32, 256, 0, stream>>>(zA[1], zB[1]);   // pass-1 acc targets
  sq_rows<<<4096, 256, 0, stream>>>(X, Y, x2, y2);

  // ---- XX and YY (symmetric): 100 half-steps, each reading only the upper
  // triangle (34 MB/matrix). 3-buffer rotation: pass p reads z[(p-1)%3],
  // accumulates z[p%3] (zeroed by pass p-1), zeroes z[(p+1)%3].
  build_k<<<dim3(64, 64), 256, 0, stream>>>(X, X, x2, x2, KA);
  build_k<<<dim3(64, 64), 256, 0, stream>>>(Y, Y, y2, y2, KB);
  for (int p = 1; p <= 100; ++p) {
    sympass2<<<dim3(528, 2), 512, 0, stream>>>(KA, KB,
                                               zA[(p - 1) % 3], zB[(p - 1) % 3],
                                               zA[p % 3], zB[p % 3],
                                               zA[(p + 1) % 3], zB[(p + 1) % 3],
                                               p == 1 ? 1 : 0);
  }
  // u raw = r_99 = z[0], v raw = r_100 = z[1]
  costpass<<<2048, 256, 0, stream>>>(KA, zA[0], zA[1], pxx);
  costpass<<<2048, 256, 0, stream>>>(KB, zB[0], zB[1], pyy);

  // ---- XY: 50 iterations of rowpass (u) + atomic colpass (v)
  build_k<<<dim3(64, 64), 256, 0, stream>>>(X, Y, x2, y2, KA);
  for (int it = 0; it < 50; ++it) {
    rowpass_xy<<<512, 512, 0, stream>>>(KA, vab[it & 1], rxy,
                                        vab[(it + 1) & 1], it == 0 ? 1 : 0);
    colpass<<<dim3(8, 128), 256, 0, stream>>>(KA, rxy, vab[(it + 1) & 1]);
  }
  costpass<<<2048, 256, 0, stream>>>(KA, rxy, vab[0], pxy);

  final_combine<<<1, 256, 0, stream>>>(pxy, pxx, pyy, out);
}

// Round 14
// 3311.942 us; speedup vs baseline: 1.3032x; 1.3032x over previous
//
#include <hip/hip_runtime.h>

#define NPTS 8192
#define DIM  128
// K stored as fp8 e4m3 scaled by S=128:  k8 = 128*exp(-C/0.1)
// recurrences on raw sums r = K8 @ w:    w = (128/8192)/(r + 128e-6)
#define WPREP(x) (0.015625f / ((x) + 1.28e-4f))

typedef short s16x8 __attribute__((ext_vector_type(8)));
typedef float f32x4 __attribute__((ext_vector_type(4)));
typedef float f32x2 __attribute__((ext_vector_type(2)));

__device__ __forceinline__ ushort f2bf(float f) {
  unsigned u = __float_as_uint(f);
  u += 0x7fffu + ((u >> 16) & 1u);   // RNE
  return (ushort)(u >> 16);
}
__device__ __forceinline__ float bf2f(ushort b) {
  return __uint_as_float(((unsigned)b) << 16);
}

// ---- fp8 e4m3 encode/decode (HW cvt preferred; self-consistent either way)
__device__ __forceinline__ unsigned char fp8_enc_sw(float f) {
  if (f < 0.015625f) {                       // subnormal: step 2^-9
    int mi = (int)rintf(f * 512.0f);
    return (unsigned char)(mi >= 8 ? 0x08 : mi);
  }
  unsigned u = __float_as_uint(f);
  unsigned r = u + 0xfffffu + ((u >> 20) & 1u);  // RNE to 3 mantissa bits
  int e = (int)((r >> 23) & 0xff) - 127;
  unsigned mant = (r >> 20) & 7u;
  if (e > 8 || (e == 8 && mant > 6)) return 0x7e;  // saturate 448
  return (unsigned char)(((e + 7) << 3) | mant);
}
__device__ __forceinline__ float fp8_dec_sw(unsigned b) {
  unsigned E = (b >> 3) & 15u, M = b & 7u;
  float n = __uint_as_float(((E + 120u) << 23) | (M << 20));
  float s = (float)M * 0.001953125f;
  return E ? n : s;
}
__device__ __forceinline__ unsigned char enc1(float f) {
#if __has_builtin(__builtin_amdgcn_cvt_pk_fp8_f32)
  return (unsigned char)(__builtin_amdgcn_cvt_pk_fp8_f32(f, f, 0, false) & 0xff);
#else
  return fp8_enc_sw(f);
#endif
}
template <bool HI>
__device__ __forceinline__ f32x2 dec2(unsigned w) {
#if __has_builtin(__builtin_amdgcn_cvt_pk_f32_fp8)
  return __builtin_amdgcn_cvt_pk_f32_fp8((int)w, HI);
#else
  f32x2 r;
  r.x = fp8_dec_sw(HI ? ((w >> 16) & 0xffu) : (w & 0xffu));
  r.y = fp8_dec_sw(HI ? (w >> 24) : ((w >> 8) & 0xffu));
  return r;
#endif
}

// LDS swizzle for the w[] vector (2-way max conflicts for lane*16 strides)
__device__ __forceinline__ int swz(int j) { return j + 2 * (j >> 5); }
#define WSZ (NPTS + 2 * (NPTS / 32) + 8)   // 8712 floats

// ---------------------------------------------------------------- zero two 8192-float buffers
__global__ __launch_bounds__(256) void init_zero2(float* __restrict__ a,
                                                  float* __restrict__ b) {
  int j = blockIdx.x * 256 + threadIdx.x;
  a[j] = 0.0f; b[j] = 0.0f;
}

// ---------------------------------------------------------------- x2 = sum(bf16(x)^2)
__global__ __launch_bounds__(256) void sq_rows(const float* __restrict__ X,
                                               const float* __restrict__ Y,
                                               float* __restrict__ x2,
                                               float* __restrict__ y2) {
  int wave = threadIdx.x >> 6, lane = threadIdx.x & 63;
  int row = blockIdx.x * 4 + wave;               // 0..16383
  const float* src = (row < NPTS) ? X + (size_t)row * DIM
                                  : Y + (size_t)(row - NPTS) * DIM;
  float2 v = *reinterpret_cast<const float2*>(src + lane * 2);
  float ax = bf2f(f2bf(v.x)), ay = bf2f(f2bf(v.y));
  float s = ax * ax + ay * ay;
  for (int off = 32; off; off >>= 1) s += __shfl_down(s, off, 64);
  if (lane == 0) {
    if (row < NPTS) x2[row] = s; else y2[row - NPTS] = s;
  }
}

// ---------------------------------------------------------------- K8 = fp8(128*exp(-10*max(a2+b2-2*A.B^T,0)))
__global__ __launch_bounds__(256) void build_k(const float* __restrict__ A,
                                               const float* __restrict__ B,
                                               const float* __restrict__ a2,
                                               const float* __restrict__ b2,
                                               unsigned char* __restrict__ K8) {
  __shared__ ushort At[128][136];   // +8 pad
  __shared__ ushort Bt[128][136];
  int t = threadIdx.x;
  int tm = blockIdx.x, tn = blockIdx.y;
  {
    int r = t >> 1;
    int c0 = (t & 1) * 64;
    const float* Ar = A + (size_t)(tm * 128 + r) * DIM + c0;
    const float* Br = B + (size_t)(tn * 128 + r) * DIM + c0;
    for (int c = 0; c < 64; c += 4) {
      float4 av = *reinterpret_cast<const float4*>(Ar + c);
      float4 bv = *reinterpret_cast<const float4*>(Br + c);
      unsigned pa0 = (unsigned)f2bf(av.x) | ((unsigned)f2bf(av.y) << 16);
      unsigned pa1 = (unsigned)f2bf(av.z) | ((unsigned)f2bf(av.w) << 16);
      unsigned pb0 = (unsigned)f2bf(bv.x) | ((unsigned)f2bf(bv.y) << 16);
      unsigned pb1 = (unsigned)f2bf(bv.z) | ((unsigned)f2bf(bv.w) << 16);
      *reinterpret_cast<unsigned*>(&At[r][c0 + c + 0]) = pa0;
      *reinterpret_cast<unsigned*>(&At[r][c0 + c + 2]) = pa1;
      *reinterpret_cast<unsigned*>(&Bt[r][c0 + c + 0]) = pb0;
      *reinterpret_cast<unsigned*>(&Bt[r][c0 + c + 2]) = pb1;
    }
  }
  __syncthreads();
  int wave = t >> 6, lane = t & 63;
  int lr = lane & 15;            // A-row / B-col within 16-tile
  int lk = (lane >> 4) * 8;      // k offset
  f32x4 acc[2][8];
  for (int mi = 0; mi < 2; ++mi)
    for (int ni = 0; ni < 8; ++ni)
      acc[mi][ni] = (f32x4){0.f, 0.f, 0.f, 0.f};
  for (int kc = 0; kc < 4; ++kc) {
    s16x8 af[2], bfr[8];
    af[0] = *reinterpret_cast<const s16x8*>(&At[wave * 32 + lr][kc * 32 + lk]);
    af[1] = *reinterpret_cast<const s16x8*>(&At[wave * 32 + 16 + lr][kc * 32 + lk]);
    for (int ni = 0; ni < 8; ++ni)
      bfr[ni] = *reinterpret_cast<const s16x8*>(&Bt[ni * 16 + lr][kc * 32 + lk]);
    for (int mi = 0; mi < 2; ++mi)
      for (int ni = 0; ni < 8; ++ni)
        acc[mi][ni] = __builtin_amdgcn_mfma_f32_16x16x32_bf16(af[mi], bfr[ni],
                                                              acc[mi][ni], 0, 0, 0);
  }
  // D layout: col = lane&15, row = (lane>>4)*4 + reg  [verified m89/m91]
  int drow = (lane >> 4) * 4;
  float a2r[2][4], b2c[8];
  for (int mi = 0; mi < 2; ++mi)
    for (int r = 0; r < 4; ++r) a2r[mi][r] = a2[tm * 128 + wave * 32 + mi * 16 + drow + r];
  for (int ni = 0; ni < 8; ++ni) b2c[ni] = b2[tn * 128 + ni * 16 + lr];
  __syncthreads();  // all LDS frag reads done; reuse At region as byte tile
  unsigned char (*O)[144] = reinterpret_cast<unsigned char (*)[144]>(&At[0][0]);
  for (int mi = 0; mi < 2; ++mi)
    for (int ni = 0; ni < 8; ++ni)
      for (int r = 0; r < 4; ++r) {
        float S = acc[mi][ni][r];
        float C = fmaxf(a2r[mi][r] + b2c[ni] - 2.0f * S, 0.0f);
        // 128*exp(-C/0.1) = 2^(7 - C*10/ln2)
        float kv = exp2f(7.0f - 14.426950408889634f * C);
        O[wave * 32 + mi * 16 + drow + r][ni * 16 + lr] = enc1(kv);
      }
  __syncthreads();
  int row = t >> 1, half = t & 1;
  const uint4* src = reinterpret_cast<const uint4*>(&O[row][half * 64]);
  uint4* dst = reinterpret_cast<uint4*>(K8 + (size_t)(tm * 128 + row) * NPTS + tn * 128 + half * 64);
#pragma unroll
  for (int k = 0; k < 4; ++k) dst[k] = src[k];
}

// ---------------------------------------------------------------- sym tile body (round-12, 256 thr)
struct SymMem {
  unsigned char T[128][132];
  float wj[128], wi[128];
  float cp[8][128];
};

__device__ __forceinline__ void sym_tile(const unsigned char* __restrict__ K8,
                                         const float* __restrict__ in,
                                         float* __restrict__ acc,
                                         float* __restrict__ zn,
                                         int tid, int init, SymMem& sm) {
  int t = threadIdx.x;
  if (tid < 32) zn[tid * 256 + t] = 0.0f;   // zero pass p+1's acc target
  // tile coords: upper triangle row-major; prefix(i) = i*64 - i*(i-1)/2
  int bi = (int)(64.5f - sqrtf(64.5f * 64.5f - 2.0f * (float)tid));
  if (bi < 0) bi = 0; if (bi > 63) bi = 63;
  while (bi > 0 && tid < bi * 64 - bi * (bi - 1) / 2) --bi;
  while (tid >= (bi + 1) * 64 - (bi + 1) * bi / 2) ++bi;
  int bj = bi + tid - (bi * 64 - bi * (bi - 1) / 2);
  if (t < 128) sm.wj[t] = init ? 1.0f : WPREP(in[bj * 128 + t]);
  else         sm.wi[t - 128] = init ? 1.0f : WPREP(in[bi * 128 + (t - 128)]);
  int r = t >> 1, h = t & 1;   // row r, half-row h (64 B each)
  const unsigned char* src = K8 + (size_t)(bi * 128 + r) * NPTS + bj * 128 + h * 64;
  uint4 q[4];
#pragma unroll
  for (int k = 0; k < 4; ++k) q[k] = *reinterpret_cast<const uint4*>(src + 16 * k);
  bool offdiag = (bi != bj);
  if (offdiag) {
#pragma unroll
    for (int k = 0; k < 4; ++k)
      *reinterpret_cast<uint4*>(&sm.T[r][h * 64 + 16 * k]) = q[k];
  }
  __syncthreads();
  // ROW phase: y[bi*128+r] += sum_c K[r][c]*wj[c]   (from registers)
  float racc = 0.f;
#pragma unroll
  for (int k = 0; k < 4; ++k) {
    const unsigned* p = &q[k].x;
#pragma unroll
    for (int e = 0; e < 4; ++e) {
      f32x2 lo = dec2<false>(p[e]), hi2 = dec2<true>(p[e]);
      int c = h * 64 + k * 16 + e * 4;
      racc = fmaf(lo.x, sm.wj[c], racc);
      racc = fmaf(lo.y, sm.wj[c + 1], racc);
      racc = fmaf(hi2.x, sm.wj[c + 2], racc);
      racc = fmaf(hi2.y, sm.wj[c + 3], racc);
    }
  }
  racc += __shfl_xor(racc, 1, 64);   // combine half-rows (2r, 2r+1)
  if (h == 0) atomicAdd(&acc[bi * 128 + r], racc);
  // COL phase (off-diag): y[bj*128+c] += sum_r T[r][c]*wi[r]
  if (offdiag) {
    int cg = t >> 3, rg = t & 7;   // cg 0..31 (128 cols), rg 0..7 (16 rows each)
    float c0 = 0.f, c1 = 0.f, c2 = 0.f, c3 = 0.f;
#pragma unroll
    for (int i = 0; i < 16; ++i) {
      int row = rg * 16 + ((i + rg * 2) & 15);   // de-phase row groups across banks
      unsigned v = *reinterpret_cast<const unsigned*>(&sm.T[row][cg * 4]);
      float wr = sm.wi[row];
      f32x2 lo = dec2<false>(v), hi2 = dec2<true>(v);
      c0 = fmaf(lo.x, wr, c0);
      c1 = fmaf(lo.y, wr, c1);
      c2 = fmaf(hi2.x, wr, c2);
      c3 = fmaf(hi2.y, wr, c3);
    }
    *reinterpret_cast<float4*>(&sm.cp[rg][cg * 4]) = make_float4(c0, c1, c2, c3);
    __syncthreads();
    if (t < 128) {
      float s = (((sm.cp[0][t] + sm.cp[1][t]) + (sm.cp[2][t] + sm.cp[3][t])) +
                 ((sm.cp[4][t] + sm.cp[5][t]) + (sm.cp[6][t] + sm.cp[7][t])));
      atomicAdd(&acc[bj * 128 + t], s);
    }
  }
}

// ---------------------------------------------------------------- depth-2 pipelined row matvec (2 rows/wave)
__device__ __forceinline__ void row_block(const unsigned char* __restrict__ K8,
                                          float* __restrict__ out,
                                          int row0, int t, const float* w) {
  int lane = t & 63;
  const unsigned char* K0 = K8 + (size_t)row0 * NPTS + lane * 16;
  const unsigned char* K1 = K0 + NPTS;
  float a0 = 0.f, b0 = 0.f, a1 = 0.f, b1 = 0.f;
  uint4 c0 = *reinterpret_cast<const uint4*>(K0);
  uint4 c1 = *reinterpret_cast<const uint4*>(K1);
#pragma unroll
  for (int rnd = 0; rnd < 8; ++rnd) {
    uint4 n0 = c0, n1 = c1;
    if (rnd < 7) {
      n0 = *reinterpret_cast<const uint4*>(K0 + (rnd + 1) * 1024);
      n1 = *reinterpret_cast<const uint4*>(K1 + (rnd + 1) * 1024);
    }
    int pb = swz(rnd * 1024 + lane * 16);
    const unsigned* p0 = &c0.x;
    const unsigned* p1 = &c1.x;
#pragma unroll
    for (int e = 0; e < 4; ++e) {
      f32x2 w0 = *reinterpret_cast<const f32x2*>(&w[pb + 4 * e]);
      f32x2 w1 = *reinterpret_cast<const f32x2*>(&w[pb + 4 * e + 2]);
      f32x2 k0l = dec2<false>(p0[e]), k0h = dec2<true>(p0[e]);
      f32x2 k1l = dec2<false>(p1[e]), k1h = dec2<true>(p1[e]);
      a0 = fmaf(k0l.x, w0.x, a0); b0 = fmaf(k0l.y, w0.y, b0);
      a0 = fmaf(k0h.x, w1.x, a0); b0 = fmaf(k0h.y, w1.y, b0);
      a1 = fmaf(k1l.x, w0.x, a1); b1 = fmaf(k1l.y, w0.y, b1);
      a1 = fmaf(k1h.x, w1.x, a1); b1 = fmaf(k1h.y, w1.y, b1);
    }
    c0 = n0; c1 = n1;
  }
  float s0 = a0 + b0, s1 = a1 + b1;
  for (int off = 32; off; off >>= 1) {
    s0 += __shfl_down(s0, off, 64);
    s1 += __shfl_down(s1, off, 64);
  }
  if (lane == 0) { out[row0] = s0; out[row0 + 1] = s1; }
}

// ---------------------------------------------------------------- fused megapass (fused path)
// grid 5184 x 256 thr: 4160 sym-tile blocks (A/B interleaved) + 1024 XY blocks
// (every 5th block). XY role alternates per launch: 0 = row pass, 1 = col pass.
union MegaMem {
  SymMem sym;                 // ~22 KB
  float w[WSZ];               // ~35 KB (xy row)
  float us[64];               // xy col
};

__global__ __launch_bounds__(256) void megapass(const unsigned char* __restrict__ KA,
                                                const unsigned char* __restrict__ KB,
                                                const unsigned char* __restrict__ KXY,
                                                const float* __restrict__ inA,
                                                const float* __restrict__ inB,
                                                float* __restrict__ accA,
                                                float* __restrict__ accB,
                                                float* __restrict__ znA,
                                                float* __restrict__ znB,
                                                const float* __restrict__ xyin,
                                                float* __restrict__ rxy,
                                                float* __restrict__ vabn,
                                                int p, int xyrole) {
  __shared__ MegaMem sm;
  int bx = blockIdx.x;
  int t = threadIdx.x;
  bool isxy = (bx % 5 == 4) && (bx < 5120);
  if (isxy) {
    int xyi = bx / 5;                       // 0..1023
    if (xyrole == 0) {
      // XY row pass: 8 rows/block; also zero the next col-accumulation buffer
      if (t < 8) vabn[xyi * 8 + t] = 0.0f;
      if (p == 1) {
#pragma unroll
        for (int k = 0; k < 32; ++k) sm.w[swz(t + 256 * k)] = 1.0f;
      } else {
        float tmp[32];
#pragma unroll
        for (int k = 0; k < 32; ++k) tmp[k] = xyin[t + 256 * k];
#pragma unroll
        for (int k = 0; k < 32; ++k) sm.w[swz(t + 256 * k)] = WPREP(tmp[k]);
      }
      __syncthreads();
      int row0 = xyi * 8 + (t >> 6) * 2;
      row_block(KXY, rxy, row0, t, sm.w);
    } else {
      // XY col pass: vabn[j] += sum_i K[i][j] * WPREP(rxy[i])
      int jb = xyi & 7, ic = xyi >> 3;
      int i0 = ic * 64;
      if (t < 64) sm.us[t] = WPREP(rxy[i0 + t]);
      __syncthreads();
      int j0 = jb * 1024 + t * 4;
      float acc0 = 0.f, acc1 = 0.f, acc2 = 0.f, acc3 = 0.f;
      for (int i = 0; i < 64; i += 8) {
        unsigned wv[8];
#pragma unroll
        for (int k = 0; k < 8; ++k)
          wv[k] = *reinterpret_cast<const unsigned*>(KXY + (size_t)(i0 + i + k) * NPTS + j0);
#pragma unroll
        for (int k = 0; k < 8; ++k) {
          float uu = sm.us[i + k];
          f32x2 lo = dec2<false>(wv[k]), hi = dec2<true>(wv[k]);
          acc0 = fmaf(lo.x, uu, acc0);
          acc1 = fmaf(lo.y, uu, acc1);
          acc2 = fmaf(hi.x, uu, acc2);
          acc3 = fmaf(hi.y, uu, acc3);
        }
      }
      atomicAdd(&vabn[j0 + 0], acc0);
      atomicAdd(&vabn[j0 + 1], acc1);
      atomicAdd(&vabn[j0 + 2], acc2);
      atomicAdd(&vabn[j0 + 3], acc3);
    }
  } else {
    int nxy_below = (bx < 5120) ? ((bx + 1) / 5) : 1024;
    int symi = bx - nxy_below;              // 0..4159
    int half = symi & 1;
    int tid = symi >> 1;                    // 0..2079
    sym_tile(half ? KB : KA, half ? inB : inA, half ? accB : accA,
             half ? znB : znA, tid, p == 1 ? 1 : 0, sm.sym);
  }
}

// ---------------------------------------------------------------- standalone kernels (fallback path)
__global__ __launch_bounds__(256) void sympass2(const unsigned char* __restrict__ KA,
                                                const unsigned char* __restrict__ KB,
                                                const float* __restrict__ inA,
                                                const float* __restrict__ inB,
                                                float* __restrict__ accA,
                                                float* __restrict__ accB,
                                                float* __restrict__ znA,
                                                float* __restrict__ znB,
                                                int init) {
  __shared__ SymMem sm;
  int half = blockIdx.y;
  sym_tile(half ? KB : KA, half ? inB : inA, half ? accB : accA,
           half ? znB : znA, blockIdx.x, init, sm);
}

__device__ __forceinline__ void prep_w512(float* w, const float* __restrict__ in, int init, int t) {
  if (init) {
#pragma unroll
    for (int k = 0; k < 16; ++k) w[swz(t + 512 * k)] = 1.0f;
  } else {
    float tmp[16];
#pragma unroll
    for (int k = 0; k < 16; ++k) tmp[k] = in[t + 512 * k];
#pragma unroll
    for (int k = 0; k < 16; ++k) w[swz(t + 512 * k)] = WPREP(tmp[k]);
  }
}

__global__ __launch_bounds__(512) void rowpass_xy(const unsigned char* __restrict__ K8,
                                                  const float* __restrict__ in,
                                                  float* __restrict__ out,
                                                  float* __restrict__ vzero,
                                                  int init) {
  __shared__ float w[WSZ];
  int t = threadIdx.x;
  if (t < 16) vzero[blockIdx.x * 16 + t] = 0.0f;
  prep_w512(w, in, init, t);
  __syncthreads();
  int row0 = blockIdx.x * 16 + (t >> 6) * 2;
  row_block(K8, out, row0, t, w);
}

__global__ __launch_bounds__(256) void colpass(const unsigned char* __restrict__ K8,
                                               const float* __restrict__ uraw,
                                               float* __restrict__ vout) {
  __shared__ float us[64];
  int t = threadIdx.x;
  int jb = blockIdx.x;
  int ic = blockIdx.y;
  int i0 = ic * 64;
  if (t < 64) us[t] = WPREP(uraw[i0 + t]);
  __syncthreads();
  int j0 = jb * 1024 + t * 4;
  float acc0 = 0.f, acc1 = 0.f, acc2 = 0.f, acc3 = 0.f;
  for (int i = 0; i < 64; i += 8) {
    unsigned wv[8];
#pragma unroll
    for (int k = 0; k < 8; ++k)
      wv[k] = *reinterpret_cast<const unsigned*>(K8 + (size_t)(i0 + i + k) * NPTS + j0);
#pragma unroll
    for (int k = 0; k < 8; ++k) {
      float uu = us[i + k];
      f32x2 lo = dec2<false>(wv[k]), hi = dec2<true>(wv[k]);
      acc0 = fmaf(lo.x, uu, acc0);
      acc1 = fmaf(lo.y, uu, acc1);
      acc2 = fmaf(hi.x, uu, acc2);
      acc3 = fmaf(hi.y, uu, acc3);
    }
  }
  atomicAdd(&vout[j0 + 0], acc0);
  atomicAdd(&vout[j0 + 1], acc1);
  atomicAdd(&vout[j0 + 2], acc2);
  atomicAdd(&vout[j0 + 3], acc3);
}

// ---------------------------------------------------------------- partial[wg] = sum_rows u_i * sum_j K*C*v_j
// C = -0.1*ln(k8/128) = 0.0693147*(7 - log2 k8);  K = k8/128 folded into u at the end
__global__ __launch_bounds__(256) void costpass(const unsigned char* __restrict__ K8,
                                                const float* __restrict__ uraw,
                                                const float* __restrict__ vraw,
                                                float* __restrict__ partial) {
  __shared__ float w[WSZ];
  __shared__ float wsum[4];
  int t = threadIdx.x;
  {
    float tmp[32];
#pragma unroll
    for (int k = 0; k < 32; ++k) tmp[k] = vraw[t + 256 * k];
#pragma unroll
    for (int k = 0; k < 32; ++k) w[swz(t + 256 * k)] = WPREP(tmp[k]);
  }
  __syncthreads();
  int wave = t >> 6, lane = t & 63;
  int row = blockIdx.x * 4 + wave;
  const unsigned char* Kr = K8 + (size_t)row * NPTS + lane * 16;
  float acc = 0.f;
  uint4 c = *reinterpret_cast<const uint4*>(Kr);
#pragma unroll
  for (int rnd = 0; rnd < 8; ++rnd) {
    uint4 n = c;
    if (rnd < 7) n = *reinterpret_cast<const uint4*>(Kr + (rnd + 1) * 1024);
    const unsigned* p = &c.x;
    int pb = swz(rnd * 1024 + lane * 16);
#pragma unroll
    for (int e = 0; e < 4; ++e) {
      f32x2 w0 = *reinterpret_cast<const f32x2*>(&w[pb + 4 * e]);
      f32x2 w1 = *reinterpret_cast<const f32x2*>(&w[pb + 4 * e + 2]);
      f32x2 kl = dec2<false>(p[e]), kh = dec2<true>(p[e]);
      float c0 = (kl.x > 0.f) ? 0.069314718f * (7.0f - __log2f(kl.x)) : 0.f;
      float c1 = (kl.y > 0.f) ? 0.069314718f * (7.0f - __log2f(kl.y)) : 0.f;
      float c2 = (kh.x > 0.f) ? 0.069314718f * (7.0f - __log2f(kh.x)) : 0.f;
      float c3 = (kh.y > 0.f) ? 0.069314718f * (7.0f - __log2f(kh.y)) : 0.f;
      acc = fmaf(kl.x * c0, w0.x, acc);
      acc = fmaf(kl.y * c1, w0.y, acc);
      acc = fmaf(kh.x * c2, w1.x, acc);
      acc = fmaf(kh.y * c3, w1.y, acc);
    }
    c = n;
  }
  for (int off = 32; off; off >>= 1) acc += __shfl_down(acc, off, 64);
  if (lane == 0) {
    float u = WPREP(uraw[row]);
    wsum[wave] = acc * u * 0.0078125f;   // fold K = k8/128
  }
  __syncthreads();
  if (t == 0) partial[blockIdx.x] = (wsum[0] + wsum[1]) + (wsum[2] + wsum[3]);
}

// ---------------------------------------------------------------- div = max(cxy - 0.5*(cxx+cyy), 0)
__global__ __launch_bounds__(256) void final_combine(const float* __restrict__ pxy,
                                                     const float* __restrict__ pxx,
                                                     const float* __restrict__ pyy,
                                                     float* __restrict__ out) {
  __shared__ float buf[3][256];
  int t = threadIdx.x;
  float s0 = 0.f, s1 = 0.f, s2 = 0.f;
  for (int i = t; i < 2048; i += 256) { s0 += pxy[i]; s1 += pxx[i]; s2 += pyy[i]; }
  buf[0][t] = s0; buf[1][t] = s1; buf[2][t] = s2;
  __syncthreads();
  for (int off = 128; off; off >>= 1) {
    if (t < off) {
      buf[0][t] += buf[0][t + off];
      buf[1][t] += buf[1][t + off];
      buf[2][t] += buf[2][t + off];
    }
    __syncthreads();
  }
  if (t == 0) {
    float div = buf[0][0] - 0.5f * (buf[1][0] + buf[2][0]);
    if (!isfinite(div)) div = 0.0f;
    out[0] = fmaxf(div, 0.0f);
  }
}

// ----------------------------------------------------------------
extern "C" void kernel_launch(void* const* d_in, const int* in_sizes, int n_in,
                              void* d_out, int out_size, void* d_ws, size_t ws_size,
                              hipStream_t stream) {
  const float* X = (const float*)d_in[0];
  const float* Y = (const float*)d_in[1];
  float* out = (float*)d_out;
  char* ws = (char*)d_ws;

  size_t off = 0;
  unsigned char* KA = (unsigned char*)(ws + off); off += (size_t)NPTS * NPTS;  // 67 MB
  unsigned char* KB = (unsigned char*)(ws + off); off += (size_t)NPTS * NPTS;  // 67 MB
  float* zA[3]; float* zB[3];
  for (int i = 0; i < 3; ++i) { zA[i] = (float*)(ws + off); off += (size_t)NPTS * 4; }
  for (int i = 0; i < 3; ++i) { zB[i] = (float*)(ws + off); off += (size_t)NPTS * 4; }
  float* rxy  = (float*)(ws + off); off += (size_t)NPTS * 4;
  float* vab0 = (float*)(ws + off); off += (size_t)NPTS * 4;
  float* vab1 = (float*)(ws + off); off += (size_t)NPTS * 4;
  float* x2   = (float*)(ws + off); off += (size_t)NPTS * 4;
  float* y2   = (float*)(ws + off); off += (size_t)NPTS * 4;
  float* pxy  = (float*)(ws + off); off += 2048 * 4;
  float* pxx  = (float*)(ws + off); off += 2048 * 4;
  float* pyy  = (float*)(ws + off); off += 2048 * 4;
  size_t need_base = off;
  unsigned char* KXY = (unsigned char*)(ws + off); off += (size_t)NPTS * NPTS; // optional 3rd K
  bool fused = (ws_size >= off);
  if (ws_size < need_base) {
    (void)hipMemsetAsync(d_out, 0, sizeof(float), stream);
    return;
  }
  float* vab[2] = {vab0, vab1};

  init_zero2<<<32, 256, 0, stream>>>(zA[1], zB[1]);   // pass-1 acc targets
  sq_rows<<<4096, 256, 0, stream>>>(X, Y, x2, y2);

  if (fused) {
    // ---- fused: each launch advances XX, YY (one half-step each) and XY
    // (alternating row/col pass). 100 launches total.
    build_k<<<dim3(64, 64), 256, 0, stream>>>(X, X, x2, x2, KA);
    build_k<<<dim3(64, 64), 256, 0, stream>>>(Y, Y, y2, y2, KB);
    build_k<<<dim3(64, 64), 256, 0, stream>>>(X, Y, x2, y2, KXY);
    for (int k = 0; k < 100; ++k) {
      int p = k + 1;
      int it = k >> 1;
      int role = k & 1;
      megapass<<<5184, 256, 0, stream>>>(KA, KB, KXY,
                                         zA[(p - 1) % 3], zB[(p - 1) % 3],
                                         zA[p % 3], zB[p % 3],
                                         zA[(p + 1) % 3], zB[(p + 1) % 3],
                                         vab[it & 1], rxy, vab[(it + 1) & 1],
                                         p, role);
    }
    costpass<<<2048, 256, 0, stream>>>(KA, zA[0], zA[1], pxx);
    costpass<<<2048, 256, 0, stream>>>(KB, zB[0], zB[1], pyy);
    costpass<<<2048, 256, 0, stream>>>(KXY, rxy, vab[0], pxy);
  } else {
    // ---- fallback (round-12 schedule): sym chains then XY chain reusing KA
    build_k<<<dim3(64, 64), 256, 0, stream>>>(X, X, x2, x2, KA);
    build_k<<<dim3(64, 64), 256, 0, stream>>>(Y, Y, y2, y2, KB);
    for (int p = 1; p <= 100; ++p) {
      sympass2<<<dim3(2080, 2), 256, 0, stream>>>(KA, KB,
                                                  zA[(p - 1) % 3], zB[(p - 1) % 3],
                                                  zA[p % 3], zB[p % 3],
                                                  zA[(p + 1) % 3], zB[(p + 1) % 3],
                                                  p == 1 ? 1 : 0);
    }
    costpass<<<2048, 256, 0, stream>>>(KA, zA[0], zA[1], pxx);
    costpass<<<2048, 256, 0, stream>>>(KB, zB[0], zB[1], pyy);
    build_k<<<dim3(64, 64), 256, 0, stream>>>(X, Y, x2, y2, KA);
    for (int it = 0; it < 50; ++it) {
      rowpass_xy<<<512, 512, 0, stream>>>(KA, vab[it & 1], rxy,
                                          vab[(it + 1) & 1], it == 0 ? 1 : 0);
      colpass<<<dim3(8, 128), 256, 0, stream>>>(KA, rxy, vab[(it + 1) & 1]);
    }
    costpass<<<2048, 256, 0, stream>>>(KA, rxy, vab[0], pxy);
  }

  final_combine<<<1, 256, 0, stream>>>(pxy, pxx, pyy, out);
}